// Round 16
// baseline (22.653 us; speedup 1.0000x reference)
//
#include <hip/hip_runtime.h>

#define IMG_H 512
#define IMG_W 512
#define NIMG  32
#define RPW   2                      // output rows per wave
#define NWAVE 4                      // waves per block
#define ROWS_PER_BLOCK (RPW * NWAVE) // 8
#define STRIPS (IMG_H / ROWS_PER_BLOCK) // 64 strips per image
#define NBLK (NIMG * STRIPS)         // 2048 blocks

typedef float f32x2 __attribute__((ext_vector_type(2)));
typedef float f32x4 __attribute__((ext_vector_type(4)));

__device__ __forceinline__ f32x2 fma2(f32x2 a, f32x2 b, f32x2 c) {
    return __builtin_elementwise_fma(a, b, c);   // -> v_pk_fma_f32
}

// Whole-wave lane shifts via DPP (one VALU op, no LDS pipe, no lgkm wait).
__device__ __forceinline__ float dpp_up1(float v) {   // lane i <- i-1, 0-fill
    int r = __builtin_amdgcn_update_dpp(0, __float_as_int(v), 0x138, 0xF, 0xF, true);
    return __int_as_float(r);
}
__device__ __forceinline__ float dpp_dn1(float v) {   // lane i <- i+1, 0-fill
    int r = __builtin_amdgcn_update_dpp(0, __float_as_int(v), 0x130, 0xF, 0xF, true);
    return __int_as_float(r);
}

// load one row's 8 columns for this lane as 4 column-pairs (zeros off-image)
__device__ __forceinline__ void rowvals(const float* __restrict__ p, int y, f32x2* x) {
    if ((unsigned)y < (unsigned)IMG_H) {
        const f32x4* q = (const f32x4*)(p + (size_t)y * IMG_W);
        f32x4 a = q[0], b = q[1];
        x[0] = a.xy; x[1] = a.zw; x[2] = b.xy; x[3] = b.zw;
    } else {
        const f32x2 z = {0.f, 0.f};
        x[0] = z; x[1] = z; x[2] = z; x[3] = z;
    }
}

// packed accumulate: 20 pk-ops replace 40 scalar ops
__device__ __forceinline__ void accrow(const f32x2* x1, const f32x2* x2,
        f32x2* s1, f32x2* s2, f32x2* s11, f32x2* s22, f32x2* s12) {
    #pragma unroll
    for (int j = 0; j < 4; ++j) {
        s1[j] += x1[j]; s2[j] += x2[j];
        s11[j] = fma2(x1[j], x1[j], s11[j]);
        s22[j] = fma2(x2[j], x2[j], s22[j]);
        s12[j] = fma2(x1[j], x2[j], s12[j]);
    }
}
__device__ __forceinline__ void subrow(const f32x2* x1, const f32x2* x2,
        f32x2* s1, f32x2* s2, f32x2* s11, f32x2* s22, f32x2* s12) {
    #pragma unroll
    for (int j = 0; j < 4; ++j) {
        s1[j] -= x1[j]; s2[j] -= x2[j];
        s11[j] = fma2(-x1[j], x1[j], s11[j]);
        s22[j] = fma2(-x2[j], x2[j], s22[j]);
        s12[j] = fma2(-x1[j], x2[j], s12[j]);
    }
}

// horizontal 7-box-sum: scalar sliding chain (serial anyway) over the
// components of the packed sums; halo via DPP wave shifts.
__device__ __forceinline__ void hbox(const f32x2* vv, f32x2* hh) {
    const float v0 = vv[0][0], v1 = vv[0][1], v2 = vv[1][0], v3 = vv[1][1],
                v4 = vv[2][0], v5 = vv[2][1], v6 = vv[3][0], v7 = vv[3][1];
    float l5 = dpp_up1(v5), l6 = dpp_up1(v6), l7 = dpp_up1(v7);
    float r0 = dpp_dn1(v0), r1 = dpp_dn1(v1), r2 = dpp_dn1(v2);
    float h0 = ((l5 + l6) + (l7 + v0)) + ((v1 + v2) + v3);
    float h1 = h0 - l5 + v4;
    float h2 = h1 - l6 + v5;
    float h3 = h2 - l7 + v6;
    float h4 = h3 - v0 + v7;
    float h5 = h4 - v1 + r0;
    float h6 = h5 - v2 + r1;
    float h7 = h6 - v3 + r2;
    hh[0][0] = h0; hh[0][1] = h1;
    hh[1][0] = h2; hh[1][1] = h3;
    hh[2][0] = h4; hh[2][1] = h5;
    hh[3][0] = h6; hh[3][1] = h7;
}

// one output row: hbox (scalar) + packed SSIM formula
__device__ __forceinline__ float rowssim(const f32x2* s1, const f32x2* s2,
        const f32x2* s11, const f32x2* s22, const f32x2* s12) {
    const f32x2 C1v = {1e-4f, 1e-4f};
    const f32x2 C2v = {9e-4f, 9e-4f};
    const f32x2 two = {2.f, 2.f};
    f32x2 h1[4], h2[4], h11[4], h22[4], h12[4];
    hbox(s1,  h1);
    hbox(s2,  h2);
    hbox(s11, h11);
    hbox(s22, h22);
    hbox(s12, h12);
    f32x2 acc = {0.f, 0.f};
    #pragma unroll
    for (int j = 0; j < 4; ++j) {
        const f32x2 mu1 = h1[j], mu2 = h2[j];
        const f32x2 mu11 = mu1 * mu1, mu22 = mu2 * mu2, mu12 = mu1 * mu2;
        const f32x2 sg1  = h11[j] - mu11;
        const f32x2 sg2  = h22[j] - mu22;
        const f32x2 sg12 = h12[j] - mu12;
        const f32x2 num = (two * mu12 + C1v) * (two * sg12 + C2v);
        const f32x2 den = (mu11 + mu22 + C1v) * (sg1 + sg2 + C2v);
        f32x2 r;
        r[0] = __builtin_amdgcn_rcpf(den[0]);
        r[1] = __builtin_amdgcn_rcpf(den[1]);
        r = r * (two - den * r);           // 1 Newton step (den > 0 always)
        acc = fma2(num, r, acc);
    }
    return acc[0] + acc[1];
}

extern "C" __global__ void __launch_bounds__(256, 2)
ssim_main(const float* __restrict__ img1, const float* __restrict__ img2,
          float* __restrict__ partials)
{
    const int tid  = threadIdx.x;
    const int lane = tid & 63;
    const int wv   = tid >> 6;

    // XCD-aware swizzle: 2048 blocks, 8 XCDs -> each XCD gets 4 whole images
    const int bid   = blockIdx.x;
    const int xcd   = bid & 7;
    const int idx   = bid >> 3;           // 0..255
    const int img   = xcd * (NIMG / 8) + (idx >> 6);
    const int strip = idx & 63;
    const int wy0   = strip * ROWS_PER_BLOCK + wv * RPW;

    const size_t base = (size_t)img * (IMG_H * IMG_W) + (size_t)(lane << 3);
    const float* p1 = img1 + base;
    const float* p2 = img2 + base;

    // Window rows q0..q7 = wy0-3 .. wy0+4; 8 row-pair loads issued upfront
    // into distinct statically-indexed buffers (one burst, single latency
    // exposure). Output rows: wy0 = box(q0..q6), wy0+1 = box(q1..q7).
    f32x2 b0a[4], b0b[4], b1a[4], b1b[4], b2a[4], b2b[4], b3a[4], b3b[4];
    f32x2 b4a[4], b4b[4], b5a[4], b5b[4], b6a[4], b6b[4], b7a[4], b7b[4];

    rowvals(p1, wy0 - 3, b0a); rowvals(p2, wy0 - 3, b0b);
    rowvals(p1, wy0 - 2, b1a); rowvals(p2, wy0 - 2, b1b);
    rowvals(p1, wy0 - 1, b2a); rowvals(p2, wy0 - 1, b2b);
    rowvals(p1, wy0 + 0, b3a); rowvals(p2, wy0 + 0, b3b);
    rowvals(p1, wy0 + 1, b4a); rowvals(p2, wy0 + 1, b4b);
    rowvals(p1, wy0 + 2, b5a); rowvals(p2, wy0 + 2, b5b);
    rowvals(p1, wy0 + 3, b6a); rowvals(p2, wy0 + 3, b6b);
    rowvals(p1, wy0 + 4, b7a); rowvals(p2, wy0 + 4, b7b);

    f32x2 s1[4], s2[4], s11[4], s22[4], s12[4];
    const f32x2 z = {0.f, 0.f};
    #pragma unroll
    for (int j = 0; j < 4; ++j) { s1[j] = s2[j] = s11[j] = s22[j] = s12[j] = z; }

    accrow(b0a, b0b, s1, s2, s11, s22, s12);   // +q0
    accrow(b1a, b1b, s1, s2, s11, s22, s12);   // +q1
    accrow(b2a, b2b, s1, s2, s11, s22, s12);   // +q2
    accrow(b3a, b3b, s1, s2, s11, s22, s12);   // +q3
    accrow(b4a, b4b, s1, s2, s11, s22, s12);   // +q4
    accrow(b5a, b5b, s1, s2, s11, s22, s12);   // +q5
    accrow(b6a, b6b, s1, s2, s11, s22, s12);   // +q6  (window q0..q6)

    float acc = rowssim(s1, s2, s11, s22, s12);           // row wy0

    subrow(b0a, b0b, s1, s2, s11, s22, s12);   // -q0
    accrow(b7a, b7b, s1, s2, s11, s22, s12);   // +q7  (window q1..q7)

    acc += rowssim(s1, s2, s11, s22, s12);                // row wy0+1

    // block reduction: wave shuffle-reduce then LDS across 4 waves
    #pragma unroll
    for (int off = 32; off; off >>= 1) acc += __shfl_down(acc, off, 64);

    __shared__ float red[NWAVE];
    if (lane == 0) red[wv] = acc;
    __syncthreads();
    if (tid == 0) {
        partials[bid] = (red[0] + red[1]) + (red[2] + red[3]);
    }
}

extern "C" __global__ void __launch_bounds__(256)
ssim_final(const float* __restrict__ partials, float* __restrict__ out)
{
    // 256 threads, 8 serial loads each, fixed order -> deterministic
    const int tid  = threadIdx.x;
    const int lane = tid & 63;
    const int wv   = tid >> 6;
    double s = 0.0;
    #pragma unroll
    for (int i = 0; i < NBLK / 256; ++i) s += (double)partials[tid + (i << 8)];
    #pragma unroll
    for (int off = 32; off; off >>= 1) s += __shfl_down(s, off, 64);
    __shared__ double sd[4];
    if (lane == 0) sd[wv] = s;
    __syncthreads();
    if (tid == 0) {
        const double t = (sd[0] + sd[1]) + (sd[2] + sd[3]);
        out[0] = (float)(1.0 - t / ((double)NIMG * IMG_H * IMG_W));
    }
}

extern "C" void kernel_launch(void* const* d_in, const int* in_sizes, int n_in,
                              void* d_out, int out_size, void* d_ws, size_t ws_size,
                              hipStream_t stream) {
    const float* img1 = (const float*)d_in[0];
    const float* img2 = (const float*)d_in[1];
    float* partials = (float*)d_ws;   // NBLK floats

    hipLaunchKernelGGL(ssim_main, dim3(NBLK), dim3(256), 0, stream,
                       img1, img2, partials);
    hipLaunchKernelGGL(ssim_final, dim3(1), dim3(256), 0, stream,
                       partials, (float*)d_out);
}